// Round 7
// baseline (721.447 us; speedup 1.0000x reference)
//
#include <hip/hip_runtime.h>

#define TLEN  1024
#define HN    64
#define LOG2E 1.4426950408889634f

// clang builtins (__builtin_amdgcn_cvt_pkrtz / fdot2) use __fp16 vectors,
// NOT _Float16 -- R7 failed to compile on exactly that.
typedef __fp16 half2v __attribute__((ext_vector_type(2)));

// One wave (64 lanes) per batch element; 1024 blocks x 64 thr = 1 wave/SIMD.
//
// R4-R6 post-mortem: two consecutive "clever permutation" schemes (dpp
// wave_ror, ds_swizzle XOR) failed with pair-internal-swap-sized errors
// (1.2-1.7e-2; cf. R1's half-scramble 6.3e-2). Their shared unverified
// ingredient: 32-lane-group semantics of cross-lane ops I never validated
// on gfx950. ABANDONED. This kernel is the verified R3 dataflow --
// BIT-IDENTICAL math to the passing 524us kernel -- with exactly one
// substitution: the 32 v_readlane hh-broadcasts become 32 UNIFORM-INDEX
// ds_bpermute broadcasts (index=4j, all lanes pull lane j<32; the
// degenerate broadcast case of the primitive __shfl_down already verified
// here in R0-R3). Readlane issues ~8cy on the VALU path (R3's 961 busy
// cy/step only closes with RL~8); bpermute issues on the DS pipe (~4-6cy)
// with latency hidden by batching 16 ahead of their consuming MACs.
// Index regs are asm-pinned so the compiler can neither rematerialize
// per-use movs nor strength-reduce the broadcast.
//
// Carried verified structure:
//  * hp[j] (lanes 0..31) = packed f16 pair {h[j], h[j+32]}, built via
//    v_permlane32_swap_b32 with DISTINCT physical regs (R1 failed on
//    coalesced "+v","+v"): v_mov into early-clobber "=&v", then swap;
//    only lanes 0..31 of the result are ever read.
//  * x staged 64 steps/chunk: one coalesced 16B/lane load per chunk,
//    2 readlane broadcasts per step, 64-step prefetch distance.
//  * FC epilogue outside the inner loop (trip 64 == FC period).
//  * 8 acc chains (2/gate), per-chain ascending-j accumulation order ==
//    R3 exactly => absmax must be EXACTLY 0.0009765625 (tripwire).
//  * log2e pre-folded into weights/biases (2*log2e for tanh gates).

#define FOR32(X) \
    X(0) X(1) X(2) X(3) X(4) X(5) X(6) X(7) \
    X(8) X(9) X(10) X(11) X(12) X(13) X(14) X(15) \
    X(16) X(17) X(18) X(19) X(20) X(21) X(22) X(23) \
    X(24) X(25) X(26) X(27) X(28) X(29) X(30) X(31)
// broadcast batch A feeds pair-groups (0..7 | 16..23), batch B (8..15 | 24..31)
#define FORBATCH_A(X) \
    X(0) X(1) X(2) X(3) X(4) X(5) X(6) X(7) \
    X(16) X(17) X(18) X(19) X(20) X(21) X(22) X(23)
#define FORBATCH_B(X) \
    X(8) X(9) X(10) X(11) X(12) X(13) X(14) X(15) \
    X(24) X(25) X(26) X(27) X(28) X(29) X(30) X(31)

__global__ __launch_bounds__(64, 1)
void lstm_bperm(const float* __restrict__ x,      // [B, T, 4]
                const float* __restrict__ W_ih,   // [256, 4]
                const float* __restrict__ W_hh,   // [256, 64]
                const float* __restrict__ b_ih,   // [256]
                const float* __restrict__ b_hh,   // [256]
                const float* __restrict__ W_fc,   // [1, 64]
                const float* __restrict__ b_fc,   // [1]
                float* __restrict__ out)          // [B, T]
{
    const int b = blockIdx.x;
    const int g = threadIdx.x;   // hidden unit 0..63 (also x-stage slot)

    __shared__ float ring[64][65];   // FC partials, stride-65: conflict-free

    const float* wr_i = W_hh + (0 * HN + g) * HN;
    const float* wr_f = W_hh + (1 * HN + g) * HN;
    const float* wr_g = W_hh + (2 * HN + g) * HN;
    const float* wr_o = W_hh + (3 * HN + g) * HN;

    // ---- 128 named half2 weight pairs {w[j], w[j+32]}, pre-scaled, pinned
#define DECL(j) half2v pi##j, pf##j, pg##j, po##j;
    FOR32(DECL)
#undef DECL

#define LOADW(j) \
    pi##j = __builtin_amdgcn_cvt_pkrtz(wr_i[j] * LOG2E, wr_i[(j) + 32] * LOG2E); \
    pf##j = __builtin_amdgcn_cvt_pkrtz(wr_f[j] * LOG2E, wr_f[(j) + 32] * LOG2E); \
    pg##j = __builtin_amdgcn_cvt_pkrtz(wr_g[j] * (2.0f * LOG2E), \
                                       wr_g[(j) + 32] * (2.0f * LOG2E)); \
    po##j = __builtin_amdgcn_cvt_pkrtz(wr_o[j] * LOG2E, wr_o[(j) + 32] * LOG2E); \
    asm volatile("" : "+v"(pi##j), "+v"(pf##j), "+v"(pg##j), "+v"(po##j));
    FOR32(LOADW)
#undef LOADW

    // ---- 32 pinned broadcast byte-indices for ds_bpermute (j*4) ----
#define DECLA(j) int ba##j = (j) * 4; asm volatile("" : "+v"(ba##j));
    FOR32(DECLA)
#undef DECLA

    // x-weights as f16 pairs (pre-scaled): 2 half2 per gate
    half2v wip0 = __builtin_amdgcn_cvt_pkrtz(W_ih[(0 * HN + g) * 4 + 0] * LOG2E,
                                             W_ih[(0 * HN + g) * 4 + 1] * LOG2E);
    half2v wip1 = __builtin_amdgcn_cvt_pkrtz(W_ih[(0 * HN + g) * 4 + 2] * LOG2E,
                                             W_ih[(0 * HN + g) * 4 + 3] * LOG2E);
    half2v wfp0 = __builtin_amdgcn_cvt_pkrtz(W_ih[(1 * HN + g) * 4 + 0] * LOG2E,
                                             W_ih[(1 * HN + g) * 4 + 1] * LOG2E);
    half2v wfp1 = __builtin_amdgcn_cvt_pkrtz(W_ih[(1 * HN + g) * 4 + 2] * LOG2E,
                                             W_ih[(1 * HN + g) * 4 + 3] * LOG2E);
    half2v wgp0 = __builtin_amdgcn_cvt_pkrtz(W_ih[(2 * HN + g) * 4 + 0] * 2.0f * LOG2E,
                                             W_ih[(2 * HN + g) * 4 + 1] * 2.0f * LOG2E);
    half2v wgp1 = __builtin_amdgcn_cvt_pkrtz(W_ih[(2 * HN + g) * 4 + 2] * 2.0f * LOG2E,
                                             W_ih[(2 * HN + g) * 4 + 3] * 2.0f * LOG2E);
    half2v wop0 = __builtin_amdgcn_cvt_pkrtz(W_ih[(3 * HN + g) * 4 + 0] * LOG2E,
                                             W_ih[(3 * HN + g) * 4 + 1] * LOG2E);
    half2v wop1 = __builtin_amdgcn_cvt_pkrtz(W_ih[(3 * HN + g) * 4 + 2] * LOG2E,
                                             W_ih[(3 * HN + g) * 4 + 3] * LOG2E);

    const float bias_i = (b_ih[0 * HN + g] + b_hh[0 * HN + g]) * LOG2E;
    const float bias_f = (b_ih[1 * HN + g] + b_hh[1 * HN + g]) * LOG2E;
    const float bias_g = (b_ih[2 * HN + g] + b_hh[2 * HN + g]) * (2.0f * LOG2E);
    const float bias_o = (b_ih[3 * HN + g] + b_hh[3 * HN + g]) * LOG2E;
    const float wfc = W_fc[g];
    const float bfc = b_fc[0];

    const float* xb = x   + (size_t)b * TLEN * 4;
    float*       ob = out + (size_t)b * TLEN;

    float h = 0.0f, c = 0.0f;
    int hp = 0;   // packed h pair {h[j], h[j+32]} per lane j<32 (start: h=0)

    // ---- x stage: lane s holds x[t0 + s] (16B coalesced per chunk) ----
    float4 xcur = *(const float4*)(xb + (size_t)g * 4);   // chunk 0

    for (int ci = 0; ci < TLEN / 64; ++ci) {
        const int cn = (ci < TLEN / 64 - 1) ? ci + 1 : ci;
        float4 xnext = *(const float4*)(xb + (size_t)(cn * 64 + g) * 4); // prefetch: 64 steps ahead

        // pack this chunk's x for readlane broadcast: {x0,x1},{x2,x3}
        const int xq0 = __builtin_bit_cast(int, __builtin_amdgcn_cvt_pkrtz(xcur.x, xcur.y));
        const int xq1 = __builtin_bit_cast(int, __builtin_amdgcn_cvt_pkrtz(xcur.z, xcur.w));

#pragma unroll 2
        for (int s = 0; s < 64; ++s) {
            // broadcast x[t] (uniform) from the stage regs: 2 readlanes
            const int xi0 = __builtin_amdgcn_readlane(xq0, s);
            const int xi1 = __builtin_amdgcn_readlane(xq1, s);
            const half2v xh0 = __builtin_bit_cast(half2v, xi0);
            const half2v xh1 = __builtin_bit_cast(half2v, xi1);

            // ---- gate accumulators: 2 chains per gate (17-deep each) ----
            float ai0 = __builtin_amdgcn_fdot2(wip0, xh0, bias_i, false);
            float af0 = __builtin_amdgcn_fdot2(wfp0, xh0, bias_f, false);
            float ag0 = __builtin_amdgcn_fdot2(wgp0, xh0, bias_g, false);
            float ao0 = __builtin_amdgcn_fdot2(wop0, xh0, bias_o, false);
            float ai1 = __builtin_amdgcn_fdot2(wip1, xh1, 0.0f, false);
            float af1 = __builtin_amdgcn_fdot2(wfp1, xh1, 0.0f, false);
            float ag1 = __builtin_amdgcn_fdot2(wgp1, xh1, 0.0f, false);
            float ao1 = __builtin_amdgcn_fdot2(wop1, xh1, 0.0f, false);

            // ---- hh matvec: bpermute broadcasts (DS pipe), 2 batches of
            //      16 issued ahead; 8 chains rotate per pair-group.
            //      Per-chain j order ascending == R3: bit-identical.
#define PRE(j) const int hj##j = __builtin_amdgcn_ds_bpermute(ba##j, hp);
#define GRP(a, b1) { \
            const half2v hA = __builtin_bit_cast(half2v, hj##a); \
            const half2v hB = __builtin_bit_cast(half2v, hj##b1); \
            ai0 = __builtin_amdgcn_fdot2(pi##a,  hA, ai0, false); \
            ai1 = __builtin_amdgcn_fdot2(pi##b1, hB, ai1, false); \
            af0 = __builtin_amdgcn_fdot2(pf##a,  hA, af0, false); \
            af1 = __builtin_amdgcn_fdot2(pf##b1, hB, af1, false); \
            ag0 = __builtin_amdgcn_fdot2(pg##a,  hA, ag0, false); \
            ag1 = __builtin_amdgcn_fdot2(pg##b1, hB, ag1, false); \
            ao0 = __builtin_amdgcn_fdot2(po##a,  hA, ao0, false); \
            ao1 = __builtin_amdgcn_fdot2(po##b1, hB, ao1, false); }

            FORBATCH_A(PRE)                 // j = 0..7, 16..23 in flight
            GRP(0, 16) GRP(1, 17) GRP(2, 18) GRP(3, 19)
            FORBATCH_B(PRE)                 // j = 8..15, 24..31 in flight
            GRP(4, 20) GRP(5, 21) GRP(6, 22) GRP(7, 23)
            GRP(8, 24) GRP(9, 25) GRP(10, 26) GRP(11, 27)
            GRP(12, 28) GRP(13, 29) GRP(14, 30) GRP(15, 31)
#undef PRE
#undef GRP

            const float ai = ai0 + ai1;
            const float af = af0 + af1;
            const float ag = ag0 + ag1;
            const float ao = ao0 + ao1;

            // ---- activations (pre-scaled): sigmoid/tanh via exp2+rcp ----
            float si = __builtin_amdgcn_rcpf(1.0f + __builtin_amdgcn_exp2f(-ai));
            float sf = __builtin_amdgcn_rcpf(1.0f + __builtin_amdgcn_exp2f(-af));
            float tg = 1.0f - 2.0f * __builtin_amdgcn_rcpf(
                                         1.0f + __builtin_amdgcn_exp2f(ag));
            float so = __builtin_amdgcn_rcpf(1.0f + __builtin_amdgcn_exp2f(-ao));

            c = sf * c + si * tg;
            float th = 1.0f - 2.0f * __builtin_amdgcn_rcpf(
                           1.0f + __builtin_amdgcn_exp2f(c * (2.0f * LOG2E)));
            h = so * th;

            // ---- hp rebuild (R2/R3-verified; lanes 0..31 used only) ----
            // pd=h, ps=copy(h); after swap: ps[l<32]=h[l+32].
            int pd = __builtin_bit_cast(int, h);
            int ps;
            asm("v_mov_b32 %1, %0\n\t"
                "v_permlane32_swap_b32 %0, %1"
                : "+v"(pd), "=&v"(ps));
            const float h_hi = __builtin_bit_cast(float, ps);
            hp = __builtin_bit_cast(int, __builtin_amdgcn_cvt_pkrtz(h, h_hi));

            // FC partial into the ring (read back once per 64 steps)
            ring[s][g] = h * wfc;
        }

        // ---- FC: transposed reduce + coalesced 64-wide store ----
        __syncthreads();   // single wave: just orders LDS w->r
        float s0 = 0.f, s1 = 0.f, s2 = 0.f, s3 = 0.f;
#pragma unroll
        for (int k = 0; k < HN; k += 4) {
            s0 += ring[g][k];
            s1 += ring[g][k + 1];
            s2 += ring[g][k + 2];
            s3 += ring[g][k + 3];
        }
        ob[ci * 64 + g] = (s0 + s1) + (s2 + s3) + bfc;

        xcur = xnext;
    }
}

extern "C" void kernel_launch(void* const* d_in, const int* in_sizes, int n_in,
                              void* d_out, int out_size, void* d_ws, size_t ws_size,
                              hipStream_t stream) {
    const float* x    = (const float*)d_in[0];
    const float* W_ih = (const float*)d_in[1];
    const float* W_hh = (const float*)d_in[2];
    const float* b_ih = (const float*)d_in[3];
    const float* b_hh = (const float*)d_in[4];
    const float* W_fc = (const float*)d_in[5];
    const float* b_fc = (const float*)d_in[6];
    float* out = (float*)d_out;

    const int B = in_sizes[0] / (TLEN * 4);   // 1024
    lstm_bperm<<<dim3(B), dim3(64), 0, stream>>>(
        x, W_ih, W_hh, b_ih, b_hh, W_fc, b_fc, out);
}

// Round 9
// 697.048 us; speedup vs baseline: 1.0350x; 1.0350x over previous
//
#include <hip/hip_runtime.h>

#define TLEN  1024
#define HN    64
#define LOG2E 1.4426950408889634f

// clang builtins (__builtin_amdgcn_cvt_pkrtz / fdot2) use __fp16 vectors,
// NOT _Float16.
typedef __fp16 half2v __attribute__((ext_vector_type(2)));

// R8 retry: identical kernel -- R8's bench died on container acquisition
// ("MI355X container failed twice"), giving zero signal. Deadlock audit
// re-done: per-step __syncthreads executed by ALL 128 threads (half==0
// guard covers only LDS/ring writes); FC barrier outside tid<64 guard;
// parity double-buffer proof in comments below. No hang path.
//
// TWO waves (128 thr) per batch element, 1024 blocks => 2048 waves =
// 2 waves/SIMD (double R3's occupancy). The hh matvec is split across the
// two lanes that share each hidden unit: unit u = w*32 + (l&31), half =
// l>>5; each lane accumulates 16 of the 32 h-pairs (64 hh-fdot2/lane vs
// R3's 128). h crosses waves via a 128B double-buffered f16 LDS array:
// per step 1 ds_write_b16 (half-0 lanes) + 4 UNIFORM-ADDRESS ds_read_b128
// per lane (broadcast; 2 distinct addrs/wave = free 2-way) -- NOT R7's 32
// bpermutes (that cost +475cy/step in lgkm waits; R7 post-mortem).
// The 32 broadcast readlanes of R3 are GONE: each lane reads its h-half
// directly from LDS, already f16-packed (pairs {h[2P],h[2P+1]}).
//
// Cross-half combine uses ONLY the production-verified direction of
// v_permlane32_swap_b32 (R2/R3: ps[l<32] = v[l+32]; distinct physical
// regs via v_mov + "=&v" -- R1 failed on operand coalescing). Half-1
// lanes' combined gate sums / h / c are garbage-by-design and NEVER
// consumed (all LDS/global writes are half==0-guarded) -- no reliance on
// lane>=32 semantics of any permutation (R4-R6 post-mortem: every
// unverified 32-lane-group assumption failed).
//
// Bias + x-contribution are PRE-HALVED into both halves (x-weights and
// biases scaled by 0.5 at init; *0.5 is exponent-only = exact), so the
// symmetric combine a + partner(a) restores them exactly.
//
// Parity double-buffer makes ONE __syncthreads per step sufficient:
// write h_t -> hbuf[t&1]; read h_{t-1} from hbuf[(t&1)^1]; the buffer
// written at step t was last read at step t-1 before that step's barrier.
// Chunk boundary safe: 64 steps/chunk keeps global parity == s&1.
//
// Carried: x staged 64 steps/chunk (one coalesced 16B/lane load per wave
// per chunk, 2 readlane broadcasts per step, 64-step prefetch distance),
// FC ring + epilogue outside the inner loop, log2e pre-folded into all
// weights/biases (2*log2e for the tanh gate).

#define FOR16(X) \
    X(0) X(1) X(2) X(3) X(4) X(5) X(6) X(7) \
    X(8) X(9) X(10) X(11) X(12) X(13) X(14) X(15)

__global__ __launch_bounds__(128, 1)
void lstm_2wave(const float* __restrict__ x,      // [B, T, 4]
                const float* __restrict__ W_ih,   // [256, 4]
                const float* __restrict__ W_hh,   // [256, 64]
                const float* __restrict__ b_ih,   // [256]
                const float* __restrict__ b_hh,   // [256]
                const float* __restrict__ W_fc,   // [1, 64]
                const float* __restrict__ b_fc,   // [1]
                float* __restrict__ out)          // [B, T]
{
    const int b    = blockIdx.x;
    const int tid  = threadIdx.x;
    const int l    = tid & 63;    // lane in wave
    const int w    = tid >> 6;    // wave 0/1
    const int lh   = l & 31;      // unit-in-wave
    const int half = l >> 5;      // which 32 h-inputs this lane sums
    const int u    = w * 32 + lh; // hidden unit 0..63

    __shared__ alignas(16) unsigned short hbuf[2][HN];  // f16 h, dbl-buffered
    __shared__ float ring[64][65];   // FC partials, stride-65: conflict-free

    if (tid < HN) { hbuf[0][tid] = 0; hbuf[1][tid] = 0; }

    const float* wr_i = W_hh + (0 * HN + u) * HN;
    const float* wr_f = W_hh + (1 * HN + u) * HN;
    const float* wr_g = W_hh + (2 * HN + u) * HN;
    const float* wr_o = W_hh + (3 * HN + u) * HN;

    // ---- 64 named half2 weight pairs {w[2P], w[2P+1]}, P = half*16+p ----
#define DECL(p) half2v pi##p, pf##p, pg##p, po##p;
    FOR16(DECL)
#undef DECL

#define LOADW(p) { \
    const int j0 = (half * 16 + (p)) * 2, j1 = j0 + 1; \
    pi##p = __builtin_amdgcn_cvt_pkrtz(wr_i[j0] * LOG2E, wr_i[j1] * LOG2E); \
    pf##p = __builtin_amdgcn_cvt_pkrtz(wr_f[j0] * LOG2E, wr_f[j1] * LOG2E); \
    pg##p = __builtin_amdgcn_cvt_pkrtz(wr_g[j0] * (2.0f * LOG2E), \
                                       wr_g[j1] * (2.0f * LOG2E)); \
    po##p = __builtin_amdgcn_cvt_pkrtz(wr_o[j0] * LOG2E, wr_o[j1] * LOG2E); \
    asm volatile("" : "+v"(pi##p), "+v"(pf##p), "+v"(pg##p), "+v"(po##p)); }
    FOR16(LOADW)
#undef LOADW

    // x-weights PRE-HALVED (both halves accumulate; combine restores).
    // tanh gate: 0.5 * 2*LOG2E = LOG2E.
    const float xs = 0.5f * LOG2E;
    half2v wip0 = __builtin_amdgcn_cvt_pkrtz(W_ih[(0 * HN + u) * 4 + 0] * xs,
                                             W_ih[(0 * HN + u) * 4 + 1] * xs);
    half2v wip1 = __builtin_amdgcn_cvt_pkrtz(W_ih[(0 * HN + u) * 4 + 2] * xs,
                                             W_ih[(0 * HN + u) * 4 + 3] * xs);
    half2v wfp0 = __builtin_amdgcn_cvt_pkrtz(W_ih[(1 * HN + u) * 4 + 0] * xs,
                                             W_ih[(1 * HN + u) * 4 + 1] * xs);
    half2v wfp1 = __builtin_amdgcn_cvt_pkrtz(W_ih[(1 * HN + u) * 4 + 2] * xs,
                                             W_ih[(1 * HN + u) * 4 + 3] * xs);
    half2v wgp0 = __builtin_amdgcn_cvt_pkrtz(W_ih[(2 * HN + u) * 4 + 0] * LOG2E,
                                             W_ih[(2 * HN + u) * 4 + 1] * LOG2E);
    half2v wgp1 = __builtin_amdgcn_cvt_pkrtz(W_ih[(2 * HN + u) * 4 + 2] * LOG2E,
                                             W_ih[(2 * HN + u) * 4 + 3] * LOG2E);
    half2v wop0 = __builtin_amdgcn_cvt_pkrtz(W_ih[(3 * HN + u) * 4 + 0] * xs,
                                             W_ih[(3 * HN + u) * 4 + 1] * xs);
    half2v wop1 = __builtin_amdgcn_cvt_pkrtz(W_ih[(3 * HN + u) * 4 + 2] * xs,
                                             W_ih[(3 * HN + u) * 4 + 3] * xs);

    // biases pre-halved too (tanh gate: 0.5*2*LOG2E = LOG2E)
    const float bias_i = 0.5f * (b_ih[0 * HN + u] + b_hh[0 * HN + u]) * LOG2E;
    const float bias_f = 0.5f * (b_ih[1 * HN + u] + b_hh[1 * HN + u]) * LOG2E;
    const float bias_g =        (b_ih[2 * HN + u] + b_hh[2 * HN + u]) * LOG2E;
    const float bias_o = 0.5f * (b_ih[3 * HN + u] + b_hh[3 * HN + u]) * LOG2E;
    const float wfc = W_fc[u];
    const float bfc = b_fc[0];

    const float* xb = x   + (size_t)b * TLEN * 4;
    float*       ob = out + (size_t)b * TLEN;

    float h = 0.0f, c = 0.0f;   // per-unit state (valid on half==0 lanes)

    // ---- x stage: lane l holds x[t0 + l] (16B coalesced per chunk) ----
    float4 xcur = *(const float4*)(xb + (size_t)l * 4);   // chunk 0

    const unsigned char* hbase = (const unsigned char*)hbuf;

    __syncthreads();   // hbuf zero-init visible to both waves

    for (int ci = 0; ci < TLEN / 64; ++ci) {
        const int cn = (ci < TLEN / 64 - 1) ? ci + 1 : ci;
        float4 xnext = *(const float4*)(xb + (size_t)(cn * 64 + l) * 4);

        // pack this chunk's x for readlane broadcast: {x0,x1},{x2,x3}
        const int xq0 = __builtin_bit_cast(int, __builtin_amdgcn_cvt_pkrtz(xcur.x, xcur.y));
        const int xq1 = __builtin_bit_cast(int, __builtin_amdgcn_cvt_pkrtz(xcur.z, xcur.w));

#pragma unroll 2
        for (int s = 0; s < 64; ++s) {
            // ---- read h[t-1]: 4 uniform ds_read_b128 of this lane's half
            const uint4* hb = (const uint4*)(hbase + ((s & 1) ^ 1) * 128
                                                   + half * 64);
            const uint4 r0 = hb[0];
            const uint4 r1 = hb[1];
            const uint4 r2 = hb[2];
            const uint4 r3 = hb[3];

            // ---- x broadcast (2 readlanes) + halved x-dot into chain A
            const int xi0 = __builtin_amdgcn_readlane(xq0, s);
            const int xi1 = __builtin_amdgcn_readlane(xq1, s);
            const half2v xh0 = __builtin_bit_cast(half2v, xi0);
            const half2v xh1 = __builtin_bit_cast(half2v, xi1);

            float aiA = __builtin_amdgcn_fdot2(wip0, xh0, bias_i, false);
            float afA = __builtin_amdgcn_fdot2(wfp0, xh0, bias_f, false);
            float agA = __builtin_amdgcn_fdot2(wgp0, xh0, bias_g, false);
            float aoA = __builtin_amdgcn_fdot2(wop0, xh0, bias_o, false);
            aiA = __builtin_amdgcn_fdot2(wip1, xh1, aiA, false);
            afA = __builtin_amdgcn_fdot2(wfp1, xh1, afA, false);
            agA = __builtin_amdgcn_fdot2(wgp1, xh1, agA, false);
            aoA = __builtin_amdgcn_fdot2(wop1, xh1, aoA, false);
            float aiB = 0.0f, afB = 0.0f, agB = 0.0f, aoB = 0.0f;

            // ---- hh matvec: 16 pair-MACs (64 fdot2), 2 chains/gate ----
#define MAC_A(p, cmp) { const half2v hh = __builtin_bit_cast(half2v, cmp); \
            aiA = __builtin_amdgcn_fdot2(pi##p, hh, aiA, false); \
            afA = __builtin_amdgcn_fdot2(pf##p, hh, afA, false); \
            agA = __builtin_amdgcn_fdot2(pg##p, hh, agA, false); \
            aoA = __builtin_amdgcn_fdot2(po##p, hh, aoA, false); }
#define MAC_B(p, cmp) { const half2v hh = __builtin_bit_cast(half2v, cmp); \
            aiB = __builtin_amdgcn_fdot2(pi##p, hh, aiB, false); \
            afB = __builtin_amdgcn_fdot2(pf##p, hh, afB, false); \
            agB = __builtin_amdgcn_fdot2(pg##p, hh, agB, false); \
            aoB = __builtin_amdgcn_fdot2(po##p, hh, aoB, false); }
            MAC_A(0,  r0.x) MAC_B(8,  r2.x)
            MAC_A(1,  r0.y) MAC_B(9,  r2.y)
            MAC_A(2,  r0.z) MAC_B(10, r2.z)
            MAC_A(3,  r0.w) MAC_B(11, r2.w)
            MAC_A(4,  r1.x) MAC_B(12, r3.x)
            MAC_A(5,  r1.y) MAC_B(13, r3.y)
            MAC_A(6,  r1.z) MAC_B(14, r3.z)
            MAC_A(7,  r1.w) MAC_B(15, r3.w)
#undef MAC_A
#undef MAC_B

            // ---- cross-half combine: verified permlane direction only.
            // ps[l<32] = v[l+32]; half-1 lanes get garbage (never used).
            float ai = aiA + aiB;
            float af = afA + afB;
            float ag = agA + agB;
            float ao = aoA + aoB;
#define COMBINE(a) { \
            int pd = __builtin_bit_cast(int, a); int ps; \
            asm("v_mov_b32 %1, %0\n\t" \
                "v_permlane32_swap_b32 %0, %1" \
                : "+v"(pd), "=&v"(ps)); \
            a += __builtin_bit_cast(float, ps); }
            COMBINE(ai) COMBINE(af) COMBINE(ag) COMBINE(ao)
#undef COMBINE

            // ---- activations (pre-scaled): sigmoid/tanh via exp2+rcp ----
            float si = __builtin_amdgcn_rcpf(1.0f + __builtin_amdgcn_exp2f(-ai));
            float sf = __builtin_amdgcn_rcpf(1.0f + __builtin_amdgcn_exp2f(-af));
            float tg = 1.0f - 2.0f * __builtin_amdgcn_rcpf(
                                         1.0f + __builtin_amdgcn_exp2f(ag));
            float so = __builtin_amdgcn_rcpf(1.0f + __builtin_amdgcn_exp2f(-ao));

            c = sf * c + si * tg;
            float th = 1.0f - 2.0f * __builtin_amdgcn_rcpf(
                           1.0f + __builtin_amdgcn_exp2f(c * (2.0f * LOG2E)));
            h = so * th;

            // ---- publish h (f16, RTZ like prior rounds) + FC partial ----
            const int hpk = __builtin_bit_cast(int,
                                __builtin_amdgcn_cvt_pkrtz(h, h));
            if (half == 0) {
                hbuf[s & 1][u] = (unsigned short)(hpk & 0xffff);
                ring[s][u] = h * wfc;
            }
            __syncthreads();   // h_t visible before step t+1 reads it
        }

        // ---- FC: wave 0 reduces; coalesced 64-wide store ----
        if (tid < 64) {
            float s0 = 0.f, s1 = 0.f, s2 = 0.f, s3 = 0.f;
#pragma unroll
            for (int k = 0; k < HN; k += 4) {
                s0 += ring[tid][k];
                s1 += ring[tid][k + 1];
                s2 += ring[tid][k + 2];
                s3 += ring[tid][k + 3];
            }
            ob[ci * 64 + tid] = (s0 + s1) + (s2 + s3) + bfc;
        }
        __syncthreads();   // ring reads done before next chunk overwrites

        xcur = xnext;
    }
}

extern "C" void kernel_launch(void* const* d_in, const int* in_sizes, int n_in,
                              void* d_out, int out_size, void* d_ws, size_t ws_size,
                              hipStream_t stream) {
    const float* x    = (const float*)d_in[0];
    const float* W_ih = (const float*)d_in[1];
    const float* W_hh = (const float*)d_in[2];
    const float* b_ih = (const float*)d_in[3];
    const float* b_hh = (const float*)d_in[4];
    const float* W_fc = (const float*)d_in[5];
    const float* b_fc = (const float*)d_in[6];
    float* out = (float*)d_out;

    const int B = in_sizes[0] / (TLEN * 4);   // 1024
    lstm_2wave<<<dim3(B), dim3(128), 0, stream>>>(
        x, W_ih, W_hh, b_ih, b_hh, W_fc, b_fc, out);
}